// Round 1
// baseline (468.189 us; speedup 1.0000x reference)
//
#include <hip/hip_runtime.h>
#include <math.h>

#define CCH 192
#define BATCH 8
#define HWSZ 16384                    // 128*128
#define NPER (CCH * HWSZ)             // per-sample elements: 3,145,728
#define NTOT ((size_t)BATCH * NPER)   // 25,165,824

// ---------- helpers ----------
__device__ __forceinline__ unsigned f2u_ord(float f) {
    unsigned u = __float_as_uint(f);
    return (u & 0x80000000u) ? ~u : (u | 0x80000000u);
}
__device__ __forceinline__ float u2f_ord(unsigned u) {
    return __uint_as_float((u & 0x80000000u) ? (u ^ 0x80000000u) : ~u);
}
__device__ __forceinline__ float fexp2(float x) { return __builtin_amdgcn_exp2f(x); }
__device__ __forceinline__ float frcp(float x)  { return __builtin_amdgcn_rcpf(x); }
// tanh(x) = 1 - 2/(exp2(x*2*log2e)+1)
__device__ __forceinline__ float ftanh(float x) {
    return 1.0f - 2.0f * frcp(fexp2(2.8853900817779268f * x) + 1.0f);
}
// sigmoid(x) = 1/(1+exp2(-x*log2e))
__device__ __forceinline__ float fsig(float x) {
    return frcp(1.0f + fexp2(-1.4426950408889634f * x));
}

// ---------- kernel A: init atomic slots + per-channel weight precompute ----------
// ws layout: uint mm[16] (min[8], max[8]); floats wtab starting at +64 floats,
// 64 floats per channel, 58 used:
//  [0..2] sp(m0)  [3..11] sp(m1)  [12..20] sp(m2)  [21..29] sp(m3)  [30..32] sp(m4)
//  [33..35] b0    [36..38] b1     [39..41] b2      [42..44] b3      [45] b4
//  [46..48] th(f0) [49..51] th(f1) [52..54] th(f2) [55..57] th(f3)
__global__ void setup_kernel(const float* __restrict__ m0, const float* __restrict__ b0,
                             const float* __restrict__ m1, const float* __restrict__ b1,
                             const float* __restrict__ m2, const float* __restrict__ b2,
                             const float* __restrict__ m3, const float* __restrict__ b3,
                             const float* __restrict__ m4, const float* __restrict__ b4,
                             const float* __restrict__ f0, const float* __restrict__ f1,
                             const float* __restrict__ f2, const float* __restrict__ f3,
                             unsigned* __restrict__ mm, float* __restrict__ wtab)
{
    int t = threadIdx.x;
    if (t < 8)             mm[t] = 0xFFFFFFFFu;   // encoded +max -> min slot
    if (t >= 8 && t < 16)  mm[t] = 0u;            // encoded -max -> max slot
    if (t < CCH) {
        float* w = wtab + t * 64;
        // stable softplus: max(v,0) + log1p(exp(-|v|))
        #pragma unroll
        for (int i = 0; i < 3; ++i) { float v = m0[t*3+i]; w[i]    = fmaxf(v,0.f)+log1pf(expf(-fabsf(v))); }
        #pragma unroll
        for (int i = 0; i < 9; ++i) { float v = m1[t*9+i]; w[3+i]  = fmaxf(v,0.f)+log1pf(expf(-fabsf(v))); }
        #pragma unroll
        for (int i = 0; i < 9; ++i) { float v = m2[t*9+i]; w[12+i] = fmaxf(v,0.f)+log1pf(expf(-fabsf(v))); }
        #pragma unroll
        for (int i = 0; i < 9; ++i) { float v = m3[t*9+i]; w[21+i] = fmaxf(v,0.f)+log1pf(expf(-fabsf(v))); }
        #pragma unroll
        for (int i = 0; i < 3; ++i) { float v = m4[t*3+i]; w[30+i] = fmaxf(v,0.f)+log1pf(expf(-fabsf(v))); }
        #pragma unroll
        for (int i = 0; i < 3; ++i) w[33+i] = b0[t*3+i];
        #pragma unroll
        for (int i = 0; i < 3; ++i) w[36+i] = b1[t*3+i];
        #pragma unroll
        for (int i = 0; i < 3; ++i) w[39+i] = b2[t*3+i];
        #pragma unroll
        for (int i = 0; i < 3; ++i) w[42+i] = b3[t*3+i];
        w[45] = b4[t];
        #pragma unroll
        for (int i = 0; i < 3; ++i) w[46+i] = tanhf(f0[t*3+i]);
        #pragma unroll
        for (int i = 0; i < 3; ++i) w[49+i] = tanhf(f1[t*3+i]);
        #pragma unroll
        for (int i = 0; i < 3; ++i) w[52+i] = tanhf(f2[t*3+i]);
        #pragma unroll
        for (int i = 0; i < 3; ++i) w[55+i] = tanhf(f3[t*3+i]);
    }
}

// ---------- kernel B: per-sample min/max ----------
#define RED_BLOCKS_PER_SAMPLE 96
__global__ __launch_bounds__(256) void minmax_kernel(const float* __restrict__ x,
                                                     unsigned* __restrict__ mm)
{
    int b   = blockIdx.x / RED_BLOCKS_PER_SAMPLE;
    int blk = blockIdx.x % RED_BLOCKS_PER_SAMPLE;
    const float4* xs = (const float4*)(x + (size_t)b * NPER);
    // NPER/4 = 786432 float4; per block 8192; per thread 32
    int base = blk * 8192;
    float mn = INFINITY, mx = -INFINITY;
    #pragma unroll 8
    for (int i = 0; i < 32; ++i) {
        float4 v = xs[base + i * 256 + threadIdx.x];
        mn = fminf(mn, fminf(fminf(v.x, v.y), fminf(v.z, v.w)));
        mx = fmaxf(mx, fmaxf(fmaxf(v.x, v.y), fmaxf(v.z, v.w)));
    }
    #pragma unroll
    for (int off = 32; off > 0; off >>= 1) {
        mn = fminf(mn, __shfl_down(mn, off, 64));
        mx = fmaxf(mx, __shfl_down(mx, off, 64));
    }
    __shared__ float smn[4], smx[4];
    int wave = threadIdx.x >> 6;
    if ((threadIdx.x & 63) == 0) { smn[wave] = mn; smx[wave] = mx; }
    __syncthreads();
    if (threadIdx.x == 0) {
        #pragma unroll
        for (int i = 1; i < 4; ++i) { mn = fminf(mn, smn[i]); mx = fmaxf(mx, smx[i]); }
        atomicMin(&mm[b],     f2u_ord(mn));
        atomicMax(&mm[8 + b], f2u_ord(mx));
    }
}

// ---------- per-element MLP ----------
__device__ __forceinline__ float eval_mlp(float x, const float* W)
{
    float a0 = fmaf(W[0], x, W[33]);
    float a1 = fmaf(W[1], x, W[34]);
    float a2 = fmaf(W[2], x, W[35]);
    a0 = fmaf(W[46], ftanh(a0), a0);
    a1 = fmaf(W[47], ftanh(a1), a1);
    a2 = fmaf(W[48], ftanh(a2), a2);

    float c0 = fmaf(W[3], a0, fmaf(W[4],  a1, fmaf(W[5],  a2, W[36])));
    float c1 = fmaf(W[6], a0, fmaf(W[7],  a1, fmaf(W[8],  a2, W[37])));
    float c2 = fmaf(W[9], a0, fmaf(W[10], a1, fmaf(W[11], a2, W[38])));
    c0 = fmaf(W[49], ftanh(c0), c0);
    c1 = fmaf(W[50], ftanh(c1), c1);
    c2 = fmaf(W[51], ftanh(c2), c2);

    float d0 = fmaf(W[12], c0, fmaf(W[13], c1, fmaf(W[14], c2, W[39])));
    float d1 = fmaf(W[15], c0, fmaf(W[16], c1, fmaf(W[17], c2, W[40])));
    float d2 = fmaf(W[18], c0, fmaf(W[19], c1, fmaf(W[20], c2, W[41])));
    d0 = fmaf(W[52], ftanh(d0), d0);
    d1 = fmaf(W[53], ftanh(d1), d1);
    d2 = fmaf(W[54], ftanh(d2), d2);

    float e0 = fmaf(W[21], d0, fmaf(W[22], d1, fmaf(W[23], d2, W[42])));
    float e1 = fmaf(W[24], d0, fmaf(W[25], d1, fmaf(W[26], d2, W[43])));
    float e2 = fmaf(W[27], d0, fmaf(W[28], d1, fmaf(W[29], d2, W[44])));
    e0 = fmaf(W[55], ftanh(e0), e0);
    e1 = fmaf(W[56], ftanh(e1), e1);
    e2 = fmaf(W[57], ftanh(e2), e2);

    return fmaf(W[30], e0, fmaf(W[31], e1, fmaf(W[32], e2, W[45])));
}

// ---------- kernel C: main elementwise ----------
// grid = BATCH * CCH * 4 blocks; each block does one quarter (4096 elems) of a
// (b,c) plane; 256 threads x 4 float4 each.
__global__ __launch_bounds__(256) void ebott_main(const float* __restrict__ x,
                                                  const unsigned* __restrict__ mm,
                                                  const float* __restrict__ wtab,
                                                  float* __restrict__ out)
{
    int blk = blockIdx.x;
    int q   = blk & 3;
    int c   = (blk >> 2) % CCH;
    int b   = blk / (4 * CCH);

    float W[58];
    const float* w = wtab + c * 64;
    #pragma unroll
    for (int i = 0; i < 58; ++i) W[i] = w[i];

    float mn = u2f_ord(mm[b]);
    float mx = u2f_ord(mm[8 + b]);
    float scale = 65535.0f / (mx - mn + 1e-12f);

    size_t base = (size_t)(b * CCH + c) * HWSZ + q * 4096;
    const float4* xin = (const float4*)(x + base);
    float4* o0 = (float4*)(out + base);
    float4* o1 = (float4*)(out + NTOT + base);
    int t = threadIdx.x;

    auto proc = [&](float xi, float& od, float& ol) {
        float d  = rintf((xi - mn) * scale) * (1.0f / 65535.0f);
        float lo = eval_mlp(d - 0.5f, W);
        float up = eval_mlp(d + 0.5f, W);
        od = d;
        ol = fmaxf(fsig(up) - fsig(lo), 1e-9f);
    };

    #pragma unroll
    for (int i = 0; i < 4; ++i) {
        float4 v = xin[i * 256 + t];
        float4 xd, lk;
        proc(v.x, xd.x, lk.x);
        proc(v.y, xd.y, lk.y);
        proc(v.z, xd.z, lk.z);
        proc(v.w, xd.w, lk.w);
        o0[i * 256 + t] = xd;
        o1[i * 256 + t] = lk;
    }
}

extern "C" void kernel_launch(void* const* d_in, const int* in_sizes, int n_in,
                              void* d_out, int out_size, void* d_ws, size_t ws_size,
                              hipStream_t stream)
{
    // setup_inputs() dict order: x, m0, b0, m1, b1, m2, b2, m3, b3, m4, b4, f0, f1, f2, f3
    const float* x  = (const float*)d_in[0];
    const float* m0 = (const float*)d_in[1];
    const float* b0 = (const float*)d_in[2];
    const float* m1 = (const float*)d_in[3];
    const float* b1 = (const float*)d_in[4];
    const float* m2 = (const float*)d_in[5];
    const float* b2 = (const float*)d_in[6];
    const float* m3 = (const float*)d_in[7];
    const float* b3 = (const float*)d_in[8];
    const float* m4 = (const float*)d_in[9];
    const float* b4 = (const float*)d_in[10];
    const float* f0 = (const float*)d_in[11];
    const float* f1 = (const float*)d_in[12];
    const float* f2 = (const float*)d_in[13];
    const float* f3 = (const float*)d_in[14];

    unsigned* mm = (unsigned*)d_ws;
    float* wtab  = (float*)d_ws + 64;
    float* out   = (float*)d_out;

    setup_kernel<<<1, 256, 0, stream>>>(m0, b0, m1, b1, m2, b2, m3, b3, m4, b4,
                                        f0, f1, f2, f3, mm, wtab);
    minmax_kernel<<<BATCH * RED_BLOCKS_PER_SAMPLE, 256, 0, stream>>>(x, mm);
    ebott_main<<<BATCH * CCH * 4, 256, 0, stream>>>(x, mm, wtab, out);
}

// Round 2
// 443.386 us; speedup vs baseline: 1.0559x; 1.0559x over previous
//
#include <hip/hip_runtime.h>
#include <hip/hip_fp16.h>
#include <math.h>

#define CCH 192
#define BATCH 8
#define HWSZ 16384                    // 128*128
#define NPER (CCH * HWSZ)             // per-sample elements: 3,145,728
#define NTOT ((size_t)BATCH * NPER)   // 25,165,824
#define INV65535 (1.0f / 65535.0f)

// ws layout (bytes):
//   [0)      uint mm[16]  (min[8] then max[8], ordered-uint encoded)
//   [256)    float wtab[192*64]  (58 used per channel)
//   [65536)  __half table[192*65536]  (likelihood LUT)  = 24 MiB
#define WS_WTAB_OFF_FLOATS 64
#define WS_TAB_OFF_BYTES   65536
#define WS_NEEDED (WS_TAB_OFF_BYTES + (size_t)CCH * 65536 * 2)

// ---------- helpers ----------
__device__ __forceinline__ unsigned f2u_ord(float f) {
    unsigned u = __float_as_uint(f);
    return (u & 0x80000000u) ? ~u : (u | 0x80000000u);
}
__device__ __forceinline__ float u2f_ord(unsigned u) {
    return __uint_as_float((u & 0x80000000u) ? (u ^ 0x80000000u) : ~u);
}
__device__ __forceinline__ float fexp2(float x) { return __builtin_amdgcn_exp2f(x); }
__device__ __forceinline__ float frcp(float x)  { return __builtin_amdgcn_rcpf(x); }
__device__ __forceinline__ float ftanh(float x) {
    return 1.0f - 2.0f * frcp(fexp2(2.8853900817779268f * x) + 1.0f);
}
__device__ __forceinline__ float fsig(float x) {
    return frcp(1.0f + fexp2(-1.4426950408889634f * x));
}

// ---------- kernel A: init atomic slots + per-channel weight precompute ----------
__global__ void setup_kernel(const float* __restrict__ m0, const float* __restrict__ b0,
                             const float* __restrict__ m1, const float* __restrict__ b1,
                             const float* __restrict__ m2, const float* __restrict__ b2,
                             const float* __restrict__ m3, const float* __restrict__ b3,
                             const float* __restrict__ m4, const float* __restrict__ b4,
                             const float* __restrict__ f0, const float* __restrict__ f1,
                             const float* __restrict__ f2, const float* __restrict__ f3,
                             unsigned* __restrict__ mm, float* __restrict__ wtab)
{
    int t = threadIdx.x;
    if (t < 8)             mm[t] = 0xFFFFFFFFu;
    if (t >= 8 && t < 16)  mm[t] = 0u;
    if (t < CCH) {
        float* w = wtab + t * 64;
        #pragma unroll
        for (int i = 0; i < 3; ++i) { float v = m0[t*3+i]; w[i]    = fmaxf(v,0.f)+log1pf(expf(-fabsf(v))); }
        #pragma unroll
        for (int i = 0; i < 9; ++i) { float v = m1[t*9+i]; w[3+i]  = fmaxf(v,0.f)+log1pf(expf(-fabsf(v))); }
        #pragma unroll
        for (int i = 0; i < 9; ++i) { float v = m2[t*9+i]; w[12+i] = fmaxf(v,0.f)+log1pf(expf(-fabsf(v))); }
        #pragma unroll
        for (int i = 0; i < 9; ++i) { float v = m3[t*9+i]; w[21+i] = fmaxf(v,0.f)+log1pf(expf(-fabsf(v))); }
        #pragma unroll
        for (int i = 0; i < 3; ++i) { float v = m4[t*3+i]; w[30+i] = fmaxf(v,0.f)+log1pf(expf(-fabsf(v))); }
        #pragma unroll
        for (int i = 0; i < 3; ++i) w[33+i] = b0[t*3+i];
        #pragma unroll
        for (int i = 0; i < 3; ++i) w[36+i] = b1[t*3+i];
        #pragma unroll
        for (int i = 0; i < 3; ++i) w[39+i] = b2[t*3+i];
        #pragma unroll
        for (int i = 0; i < 3; ++i) w[42+i] = b3[t*3+i];
        w[45] = b4[t];
        #pragma unroll
        for (int i = 0; i < 3; ++i) w[46+i] = tanhf(f0[t*3+i]);
        #pragma unroll
        for (int i = 0; i < 3; ++i) w[49+i] = tanhf(f1[t*3+i]);
        #pragma unroll
        for (int i = 0; i < 3; ++i) w[52+i] = tanhf(f2[t*3+i]);
        #pragma unroll
        for (int i = 0; i < 3; ++i) w[55+i] = tanhf(f3[t*3+i]);
    }
}

// ---------- kernel B: per-sample min/max ----------
#define RED_BLOCKS_PER_SAMPLE 192
__global__ __launch_bounds__(256) void minmax_kernel(const float* __restrict__ x,
                                                     unsigned* __restrict__ mm)
{
    int b   = blockIdx.x / RED_BLOCKS_PER_SAMPLE;
    int blk = blockIdx.x % RED_BLOCKS_PER_SAMPLE;
    const float4* xs = (const float4*)(x + (size_t)b * NPER);
    // NPER/4 = 786432 float4; per block 4096; per thread 16
    int base = blk * 4096;
    float mn = INFINITY, mx = -INFINITY;
    #pragma unroll
    for (int i = 0; i < 16; ++i) {
        float4 v = xs[base + i * 256 + threadIdx.x];
        mn = fminf(mn, fminf(fminf(v.x, v.y), fminf(v.z, v.w)));
        mx = fmaxf(mx, fmaxf(fmaxf(v.x, v.y), fmaxf(v.z, v.w)));
    }
    #pragma unroll
    for (int off = 32; off > 0; off >>= 1) {
        mn = fminf(mn, __shfl_down(mn, off, 64));
        mx = fmaxf(mx, __shfl_down(mx, off, 64));
    }
    __shared__ float smn[4], smx[4];
    int wave = threadIdx.x >> 6;
    if ((threadIdx.x & 63) == 0) { smn[wave] = mn; smx[wave] = mx; }
    __syncthreads();
    if (threadIdx.x == 0) {
        #pragma unroll
        for (int i = 1; i < 4; ++i) { mn = fminf(mn, smn[i]); mx = fmaxf(mx, smx[i]); }
        atomicMin(&mm[b],     f2u_ord(mn));
        atomicMax(&mm[8 + b], f2u_ord(mx));
    }
}

// ---------- per-element MLP ----------
__device__ __forceinline__ float eval_mlp(float x, const float* W)
{
    float a0 = fmaf(W[0], x, W[33]);
    float a1 = fmaf(W[1], x, W[34]);
    float a2 = fmaf(W[2], x, W[35]);
    a0 = fmaf(W[46], ftanh(a0), a0);
    a1 = fmaf(W[47], ftanh(a1), a1);
    a2 = fmaf(W[48], ftanh(a2), a2);

    float c0 = fmaf(W[3], a0, fmaf(W[4],  a1, fmaf(W[5],  a2, W[36])));
    float c1 = fmaf(W[6], a0, fmaf(W[7],  a1, fmaf(W[8],  a2, W[37])));
    float c2 = fmaf(W[9], a0, fmaf(W[10], a1, fmaf(W[11], a2, W[38])));
    c0 = fmaf(W[49], ftanh(c0), c0);
    c1 = fmaf(W[50], ftanh(c1), c1);
    c2 = fmaf(W[51], ftanh(c2), c2);

    float d0 = fmaf(W[12], c0, fmaf(W[13], c1, fmaf(W[14], c2, W[39])));
    float d1 = fmaf(W[15], c0, fmaf(W[16], c1, fmaf(W[17], c2, W[40])));
    float d2 = fmaf(W[18], c0, fmaf(W[19], c1, fmaf(W[20], c2, W[41])));
    d0 = fmaf(W[52], ftanh(d0), d0);
    d1 = fmaf(W[53], ftanh(d1), d1);
    d2 = fmaf(W[54], ftanh(d2), d2);

    float e0 = fmaf(W[21], d0, fmaf(W[22], d1, fmaf(W[23], d2, W[42])));
    float e1 = fmaf(W[24], d0, fmaf(W[25], d1, fmaf(W[26], d2, W[43])));
    float e2 = fmaf(W[27], d0, fmaf(W[28], d1, fmaf(W[29], d2, W[44])));
    e0 = fmaf(W[55], ftanh(e0), e0);
    e1 = fmaf(W[56], ftanh(e1), e1);
    e2 = fmaf(W[57], ftanh(e2), e2);

    return fmaf(W[30], e0, fmaf(W[31], e1, fmaf(W[32], e2, W[45])));
}

__device__ __forceinline__ float eval_lik(float d, const float* W)
{
    float lo = eval_mlp(d - 0.5f, W);
    float up = eval_mlp(d + 0.5f, W);
    return fmaxf(fsig(up) - fsig(lo), 1e-9f);
}

// ---------- kernel T: likelihood LUT build ----------
// grid = 192 * 128 blocks of 256 threads; each thread does 2 consecutive k.
__global__ __launch_bounds__(256) void table_kernel(const float* __restrict__ wtab,
                                                    __half* __restrict__ tab)
{
    int c  = blockIdx.x >> 7;
    int k0 = (((blockIdx.x & 127) << 8) + threadIdx.x) << 1;   // even k in [0,65536)

    float W[58];
    const float* w = wtab + c * 64;
    #pragma unroll
    for (int i = 0; i < 58; ++i) W[i] = w[i];

    float l0 = eval_lik((float)k0 * INV65535, W);
    float l1 = eval_lik((float)(k0 + 1) * INV65535, W);

    __half2 h;
    h.x = __float2half_rn(l0);
    h.y = __float2half_rn(l1);
    ((__half2*)(tab + (size_t)c * 65536))[k0 >> 1] = h;
}

// ---------- kernel G: quantize + LUT gather + write ----------
// grid = 192 ch * 4 sample-pairs = 768 blocks of 1024 threads.
// Each block stages its channel's 128 KB fp16 table into LDS, then processes
// 2 sample-planes (32768 pixels).
__global__ __launch_bounds__(1024) void gather_kernel(const float* __restrict__ x,
                                                      const unsigned* __restrict__ mm,
                                                      const __half* __restrict__ tab,
                                                      float* __restrict__ out)
{
    __shared__ __align__(16) __half ltab[65536];   // 128 KB

    int c    = blockIdx.x >> 2;
    int pair = blockIdx.x & 3;
    int t    = threadIdx.x;

    // stage table: 8192 float4 (16B) over 1024 threads = 8 iters
    const float4* tsrc = (const float4*)(tab + (size_t)c * 65536);
    float4* tdst = (float4*)ltab;
    #pragma unroll
    for (int i = 0; i < 8; ++i) tdst[i * 1024 + t] = tsrc[i * 1024 + t];
    __syncthreads();

    #pragma unroll
    for (int s = 0; s < 2; ++s) {
        int b = pair * 2 + s;
        float mn = u2f_ord(mm[b]);
        float mx = u2f_ord(mm[8 + b]);
        float scale = 65535.0f / (mx - mn + 1e-12f);

        size_t base = ((size_t)b * CCH + c) * HWSZ;
        const float4* xin = (const float4*)(x + base);
        float4* o0 = (float4*)(out + base);
        float4* o1 = (float4*)(out + NTOT + base);

        auto proc = [&](float xi, float& od, float& ol) {
            float kf = rintf((xi - mn) * scale);
            int ki = (int)kf;
            ki = ki < 0 ? 0 : (ki > 65535 ? 65535 : ki);
            od = kf * INV65535;
            ol = __half2float(ltab[ki]);
        };

        #pragma unroll
        for (int i = 0; i < 4; ++i) {
            float4 v = xin[i * 1024 + t];
            float4 xd, lk;
            proc(v.x, xd.x, lk.x);
            proc(v.y, xd.y, lk.y);
            proc(v.z, xd.z, lk.z);
            proc(v.w, xd.w, lk.w);
            o0[i * 1024 + t] = xd;
            o1[i * 1024 + t] = lk;
        }
    }
}

// ---------- fallback: direct elementwise (if ws too small for LUT) ----------
__global__ __launch_bounds__(256) void ebott_main(const float* __restrict__ x,
                                                  const unsigned* __restrict__ mm,
                                                  const float* __restrict__ wtab,
                                                  float* __restrict__ out)
{
    int blk = blockIdx.x;
    int q   = blk & 3;
    int c   = (blk >> 2) % CCH;
    int b   = blk / (4 * CCH);

    float W[58];
    const float* w = wtab + c * 64;
    #pragma unroll
    for (int i = 0; i < 58; ++i) W[i] = w[i];

    float mn = u2f_ord(mm[b]);
    float mx = u2f_ord(mm[8 + b]);
    float scale = 65535.0f / (mx - mn + 1e-12f);

    size_t base = (size_t)(b * CCH + c) * HWSZ + q * 4096;
    const float4* xin = (const float4*)(x + base);
    float4* o0 = (float4*)(out + base);
    float4* o1 = (float4*)(out + NTOT + base);
    int t = threadIdx.x;

    auto proc = [&](float xi, float& od, float& ol) {
        float d = rintf((xi - mn) * scale) * INV65535;
        od = d;
        ol = eval_lik(d, W);
    };

    #pragma unroll
    for (int i = 0; i < 4; ++i) {
        float4 v = xin[i * 256 + t];
        float4 xd, lk;
        proc(v.x, xd.x, lk.x);
        proc(v.y, xd.y, lk.y);
        proc(v.z, xd.z, lk.z);
        proc(v.w, xd.w, lk.w);
        o0[i * 256 + t] = xd;
        o1[i * 256 + t] = lk;
    }
}

extern "C" void kernel_launch(void* const* d_in, const int* in_sizes, int n_in,
                              void* d_out, int out_size, void* d_ws, size_t ws_size,
                              hipStream_t stream)
{
    const float* x  = (const float*)d_in[0];
    const float* m0 = (const float*)d_in[1];
    const float* b0 = (const float*)d_in[2];
    const float* m1 = (const float*)d_in[3];
    const float* b1 = (const float*)d_in[4];
    const float* m2 = (const float*)d_in[5];
    const float* b2 = (const float*)d_in[6];
    const float* m3 = (const float*)d_in[7];
    const float* b3 = (const float*)d_in[8];
    const float* m4 = (const float*)d_in[9];
    const float* b4 = (const float*)d_in[10];
    const float* f0 = (const float*)d_in[11];
    const float* f1 = (const float*)d_in[12];
    const float* f2 = (const float*)d_in[13];
    const float* f3 = (const float*)d_in[14];

    unsigned* mm = (unsigned*)d_ws;
    float* wtab  = (float*)d_ws + WS_WTAB_OFF_FLOATS;
    __half* tab  = (__half*)((char*)d_ws + WS_TAB_OFF_BYTES);
    float* out   = (float*)d_out;

    setup_kernel<<<1, 256, 0, stream>>>(m0, b0, m1, b1, m2, b2, m3, b3, m4, b4,
                                        f0, f1, f2, f3, mm, wtab);
    minmax_kernel<<<BATCH * RED_BLOCKS_PER_SAMPLE, 256, 0, stream>>>(x, mm);

    if (ws_size >= WS_NEEDED) {
        table_kernel<<<CCH * 128, 256, 0, stream>>>(wtab, tab);
        gather_kernel<<<CCH * 4, 1024, 0, stream>>>(x, mm, tab, out);
    } else {
        ebott_main<<<BATCH * CCH * 4, 256, 0, stream>>>(x, mm, wtab, out);
    }
}

// Round 3
// 358.031 us; speedup vs baseline: 1.3077x; 1.2384x over previous
//
#include <hip/hip_runtime.h>
#include <math.h>

#define CCH 192
#define BATCH 8
#define HWSZ 16384                    // 128*128
#define NPER (CCH * HWSZ)             // per-sample elements: 3,145,728
#define NTOT ((size_t)BATCH * NPER)   // 25,165,824
#define INV65535 (1.0f / 65535.0f)

// LUT: 8193 knots over d in [0,1], stride padded to 8196 floats (16B aligned)
#define TABN    8193
#define TABSTR  8196
#define TSCALE  (8192.0f / 65535.0f)

// ws layout (bytes):
//   [0)      uint mm[16]  (min[8] then max[8], ordered-uint encoded)
//   [256)    float wtab[192*64]  (58 used per channel)
//   [65536)  float table[192*8196]  (likelihood LUT, ~6.3 MB)
#define WS_WTAB_OFF_FLOATS 64
#define WS_TAB_OFF_BYTES   65536
#define WS_NEEDED (WS_TAB_OFF_BYTES + (size_t)CCH * TABSTR * 4)

// ---------- helpers ----------
__device__ __forceinline__ unsigned f2u_ord(float f) {
    unsigned u = __float_as_uint(f);
    return (u & 0x80000000u) ? ~u : (u | 0x80000000u);
}
__device__ __forceinline__ float u2f_ord(unsigned u) {
    return __uint_as_float((u & 0x80000000u) ? (u ^ 0x80000000u) : ~u);
}
__device__ __forceinline__ float fexp2(float x) { return __builtin_amdgcn_exp2f(x); }
__device__ __forceinline__ float frcp(float x)  { return __builtin_amdgcn_rcpf(x); }
__device__ __forceinline__ float ftanh(float x) {
    return 1.0f - 2.0f * frcp(fexp2(2.8853900817779268f * x) + 1.0f);
}
__device__ __forceinline__ float fsig(float x) {
    return frcp(1.0f + fexp2(-1.4426950408889634f * x));
}

// ---------- kernel A: init atomic slots + per-channel weight precompute ----------
__global__ void setup_kernel(const float* __restrict__ m0, const float* __restrict__ b0,
                             const float* __restrict__ m1, const float* __restrict__ b1,
                             const float* __restrict__ m2, const float* __restrict__ b2,
                             const float* __restrict__ m3, const float* __restrict__ b3,
                             const float* __restrict__ m4, const float* __restrict__ b4,
                             const float* __restrict__ f0, const float* __restrict__ f1,
                             const float* __restrict__ f2, const float* __restrict__ f3,
                             unsigned* __restrict__ mm, float* __restrict__ wtab)
{
    int t = threadIdx.x;
    if (t < 8)             mm[t] = 0xFFFFFFFFu;
    if (t >= 8 && t < 16)  mm[t] = 0u;
    if (t < CCH) {
        float* w = wtab + t * 64;
        #pragma unroll
        for (int i = 0; i < 3; ++i) { float v = m0[t*3+i]; w[i]    = fmaxf(v,0.f)+log1pf(expf(-fabsf(v))); }
        #pragma unroll
        for (int i = 0; i < 9; ++i) { float v = m1[t*9+i]; w[3+i]  = fmaxf(v,0.f)+log1pf(expf(-fabsf(v))); }
        #pragma unroll
        for (int i = 0; i < 9; ++i) { float v = m2[t*9+i]; w[12+i] = fmaxf(v,0.f)+log1pf(expf(-fabsf(v))); }
        #pragma unroll
        for (int i = 0; i < 9; ++i) { float v = m3[t*9+i]; w[21+i] = fmaxf(v,0.f)+log1pf(expf(-fabsf(v))); }
        #pragma unroll
        for (int i = 0; i < 3; ++i) { float v = m4[t*3+i]; w[30+i] = fmaxf(v,0.f)+log1pf(expf(-fabsf(v))); }
        #pragma unroll
        for (int i = 0; i < 3; ++i) w[33+i] = b0[t*3+i];
        #pragma unroll
        for (int i = 0; i < 3; ++i) w[36+i] = b1[t*3+i];
        #pragma unroll
        for (int i = 0; i < 3; ++i) w[39+i] = b2[t*3+i];
        #pragma unroll
        for (int i = 0; i < 3; ++i) w[42+i] = b3[t*3+i];
        w[45] = b4[t];
        #pragma unroll
        for (int i = 0; i < 3; ++i) w[46+i] = tanhf(f0[t*3+i]);
        #pragma unroll
        for (int i = 0; i < 3; ++i) w[49+i] = tanhf(f1[t*3+i]);
        #pragma unroll
        for (int i = 0; i < 3; ++i) w[52+i] = tanhf(f2[t*3+i]);
        #pragma unroll
        for (int i = 0; i < 3; ++i) w[55+i] = tanhf(f3[t*3+i]);
    }
}

// ---------- kernel B: per-sample min/max ----------
#define RED_BLOCKS_PER_SAMPLE 192
__global__ __launch_bounds__(256) void minmax_kernel(const float* __restrict__ x,
                                                     unsigned* __restrict__ mm)
{
    int b   = blockIdx.x / RED_BLOCKS_PER_SAMPLE;
    int blk = blockIdx.x % RED_BLOCKS_PER_SAMPLE;
    const float4* xs = (const float4*)(x + (size_t)b * NPER);
    int base = blk * 4096;
    float mn = INFINITY, mx = -INFINITY;
    #pragma unroll
    for (int i = 0; i < 16; ++i) {
        float4 v = xs[base + i * 256 + threadIdx.x];
        mn = fminf(mn, fminf(fminf(v.x, v.y), fminf(v.z, v.w)));
        mx = fmaxf(mx, fmaxf(fmaxf(v.x, v.y), fmaxf(v.z, v.w)));
    }
    #pragma unroll
    for (int off = 32; off > 0; off >>= 1) {
        mn = fminf(mn, __shfl_down(mn, off, 64));
        mx = fmaxf(mx, __shfl_down(mx, off, 64));
    }
    __shared__ float smn[4], smx[4];
    int wave = threadIdx.x >> 6;
    if ((threadIdx.x & 63) == 0) { smn[wave] = mn; smx[wave] = mx; }
    __syncthreads();
    if (threadIdx.x == 0) {
        #pragma unroll
        for (int i = 1; i < 4; ++i) { mn = fminf(mn, smn[i]); mx = fmaxf(mx, smx[i]); }
        atomicMin(&mm[b],     f2u_ord(mn));
        atomicMax(&mm[8 + b], f2u_ord(mx));
    }
}

// ---------- per-element MLP ----------
__device__ __forceinline__ float eval_mlp(float x, const float* W)
{
    float a0 = fmaf(W[0], x, W[33]);
    float a1 = fmaf(W[1], x, W[34]);
    float a2 = fmaf(W[2], x, W[35]);
    a0 = fmaf(W[46], ftanh(a0), a0);
    a1 = fmaf(W[47], ftanh(a1), a1);
    a2 = fmaf(W[48], ftanh(a2), a2);

    float c0 = fmaf(W[3], a0, fmaf(W[4],  a1, fmaf(W[5],  a2, W[36])));
    float c1 = fmaf(W[6], a0, fmaf(W[7],  a1, fmaf(W[8],  a2, W[37])));
    float c2 = fmaf(W[9], a0, fmaf(W[10], a1, fmaf(W[11], a2, W[38])));
    c0 = fmaf(W[49], ftanh(c0), c0);
    c1 = fmaf(W[50], ftanh(c1), c1);
    c2 = fmaf(W[51], ftanh(c2), c2);

    float d0 = fmaf(W[12], c0, fmaf(W[13], c1, fmaf(W[14], c2, W[39])));
    float d1 = fmaf(W[15], c0, fmaf(W[16], c1, fmaf(W[17], c2, W[40])));
    float d2 = fmaf(W[18], c0, fmaf(W[19], c1, fmaf(W[20], c2, W[41])));
    d0 = fmaf(W[52], ftanh(d0), d0);
    d1 = fmaf(W[53], ftanh(d1), d1);
    d2 = fmaf(W[54], ftanh(d2), d2);

    float e0 = fmaf(W[21], d0, fmaf(W[22], d1, fmaf(W[23], d2, W[42])));
    float e1 = fmaf(W[24], d0, fmaf(W[25], d1, fmaf(W[26], d2, W[43])));
    float e2 = fmaf(W[27], d0, fmaf(W[28], d1, fmaf(W[29], d2, W[44])));
    e0 = fmaf(W[55], ftanh(e0), e0);
    e1 = fmaf(W[56], ftanh(e1), e1);
    e2 = fmaf(W[57], ftanh(e2), e2);

    return fmaf(W[30], e0, fmaf(W[31], e1, fmaf(W[32], e2, W[45])));
}

__device__ __forceinline__ float eval_lik(float d, const float* W)
{
    float lo = eval_mlp(d - 0.5f, W);
    float up = eval_mlp(d + 0.5f, W);
    return fmaxf(fsig(up) - fsig(lo), 1e-9f);
}

// ---------- kernel T: likelihood LUT build (8193 knots per channel) ----------
// grid = 192 * 33 blocks of 256; c uniform per block.
__global__ __launch_bounds__(256) void table_kernel(const float* __restrict__ wtab,
                                                    float* __restrict__ tab)
{
    int c = blockIdx.x / 33;
    int j = (blockIdx.x % 33) * 256 + threadIdx.x;
    if (j >= TABN) return;

    float W[58];
    const float* w = wtab + c * 64;
    #pragma unroll
    for (int i = 0; i < 58; ++i) W[i] = w[i];

    float d = (float)j * (1.0f / 8192.0f);
    tab[(size_t)c * TABSTR + j] = eval_lik(d, W);
}

// ---------- kernel G: quantize + LDS-LUT lerp + write ----------
// grid = 192 ch * 8 samples = 1536 blocks of 256 threads; one (b,c) plane each.
__global__ __launch_bounds__(256) void gather_kernel(const float* __restrict__ x,
                                                     const unsigned* __restrict__ mm,
                                                     const float* __restrict__ tab,
                                                     float* __restrict__ out)
{
    __shared__ __align__(16) float ltab[TABN + 3];   // ~32.8 KB

    int c = blockIdx.x >> 3;
    int b = blockIdx.x & 7;
    int t = threadIdx.x;

    // stage channel table: 2048 float4 over 256 threads = 8 iters + tail elem
    const float4* tsrc = (const float4*)(tab + (size_t)c * TABSTR);
    float4* tdst = (float4*)ltab;
    #pragma unroll
    for (int i = 0; i < 8; ++i) tdst[i * 256 + t] = tsrc[i * 256 + t];
    if (t == 0) ltab[8192] = tab[(size_t)c * TABSTR + 8192];
    __syncthreads();

    float mn = u2f_ord(mm[b]);
    float mx = u2f_ord(mm[8 + b]);
    float scale = 65535.0f / (mx - mn + 1e-12f);

    size_t base = ((size_t)b * CCH + c) * HWSZ;
    const float4* xin = (const float4*)(x + base);
    float4* o0 = (float4*)(out + base);
    float4* o1 = (float4*)(out + NTOT + base);

    auto proc = [&](float xi, float& od, float& ol) {
        float kf   = rintf((xi - mn) * scale);
        od         = kf * INV65535;
        float tpos = kf * TSCALE;
        int   j    = (int)tpos;
        j = j > 8191 ? 8191 : j;
        float frac = tpos - (float)j;
        float t0 = ltab[j];
        float t1 = ltab[j + 1];
        ol = fmaxf(fmaf(frac, t1 - t0, t0), 1e-9f);
    };

    #pragma unroll
    for (int i = 0; i < 16; ++i) {
        float4 v = xin[i * 256 + t];
        float4 xd, lk;
        proc(v.x, xd.x, lk.x);
        proc(v.y, xd.y, lk.y);
        proc(v.z, xd.z, lk.z);
        proc(v.w, xd.w, lk.w);
        o0[i * 256 + t] = xd;
        o1[i * 256 + t] = lk;
    }
}

// ---------- fallback: direct elementwise (if ws too small for LUT) ----------
__global__ __launch_bounds__(256) void ebott_main(const float* __restrict__ x,
                                                  const unsigned* __restrict__ mm,
                                                  const float* __restrict__ wtab,
                                                  float* __restrict__ out)
{
    int blk = blockIdx.x;
    int q   = blk & 3;
    int c   = (blk >> 2) % CCH;
    int b   = blk / (4 * CCH);

    float W[58];
    const float* w = wtab + c * 64;
    #pragma unroll
    for (int i = 0; i < 58; ++i) W[i] = w[i];

    float mn = u2f_ord(mm[b]);
    float mx = u2f_ord(mm[8 + b]);
    float scale = 65535.0f / (mx - mn + 1e-12f);

    size_t base = (size_t)(b * CCH + c) * HWSZ + q * 4096;
    const float4* xin = (const float4*)(x + base);
    float4* o0 = (float4*)(out + base);
    float4* o1 = (float4*)(out + NTOT + base);
    int t = threadIdx.x;

    auto proc = [&](float xi, float& od, float& ol) {
        float d = rintf((xi - mn) * scale) * INV65535;
        od = d;
        ol = eval_lik(d, W);
    };

    #pragma unroll
    for (int i = 0; i < 4; ++i) {
        float4 v = xin[i * 256 + t];
        float4 xd, lk;
        proc(v.x, xd.x, lk.x);
        proc(v.y, xd.y, lk.y);
        proc(v.z, xd.z, lk.z);
        proc(v.w, xd.w, lk.w);
        o0[i * 256 + t] = xd;
        o1[i * 256 + t] = lk;
    }
}

extern "C" void kernel_launch(void* const* d_in, const int* in_sizes, int n_in,
                              void* d_out, int out_size, void* d_ws, size_t ws_size,
                              hipStream_t stream)
{
    const float* x  = (const float*)d_in[0];
    const float* m0 = (const float*)d_in[1];
    const float* b0 = (const float*)d_in[2];
    const float* m1 = (const float*)d_in[3];
    const float* b1 = (const float*)d_in[4];
    const float* m2 = (const float*)d_in[5];
    const float* b2 = (const float*)d_in[6];
    const float* m3 = (const float*)d_in[7];
    const float* b3 = (const float*)d_in[8];
    const float* m4 = (const float*)d_in[9];
    const float* b4 = (const float*)d_in[10];
    const float* f0 = (const float*)d_in[11];
    const float* f1 = (const float*)d_in[12];
    const float* f2 = (const float*)d_in[13];
    const float* f3 = (const float*)d_in[14];

    unsigned* mm = (unsigned*)d_ws;
    float* wtab  = (float*)d_ws + WS_WTAB_OFF_FLOATS;
    float* tab   = (float*)((char*)d_ws + WS_TAB_OFF_BYTES);
    float* out   = (float*)d_out;

    setup_kernel<<<1, 256, 0, stream>>>(m0, b0, m1, b1, m2, b2, m3, b3, m4, b4,
                                        f0, f1, f2, f3, mm, wtab);
    minmax_kernel<<<BATCH * RED_BLOCKS_PER_SAMPLE, 256, 0, stream>>>(x, mm);

    if (ws_size >= WS_NEEDED) {
        table_kernel<<<CCH * 33, 256, 0, stream>>>(wtab, tab);
        gather_kernel<<<CCH * BATCH, 256, 0, stream>>>(x, mm, tab, out);
    } else {
        ebott_main<<<BATCH * CCH * 4, 256, 0, stream>>>(x, mm, wtab, out);
    }
}